// Round 5
// baseline (1352.066 us; speedup 1.0000x reference)
//
#include <hip/hip_runtime.h>
#include <hip/hip_bf16.h>
#include <math.h>

typedef __attribute__((ext_vector_type(4))) int i32x4;
typedef __attribute__((ext_vector_type(4))) float f32x4;

#define BM 256
#define BN 256
#define BKB 128  // K-bytes per tile = 128 int8 elements

__device__ __forceinline__ void glds16(const void* g, void* l) {
  __builtin_amdgcn_global_load_lds(
      (const __attribute__((address_space(1))) void*)g,
      (__attribute__((address_space(3))) void*)l, 16, 0, 0);
}

// ---------------- prep_x: per-token int8 quant, store q as i8 --------------
__global__ __launch_bounds__(256) void prep_x(const float* __restrict__ x,
                                              char* __restrict__ xq,
                                              float* __restrict__ sct,
                                              float* __restrict__ zpt,
                                              int I) {
  const int wave = threadIdx.x >> 6, lane = threadIdx.x & 63;
  const int row = blockIdx.x * 4 + wave;
  const float4* xr = (const float4*)(x + (size_t)row * I);
  float4 v[16];  // I/4 float4 per row / 64 lanes = 16 (I = 4096)
#pragma unroll
  for (int j = 0; j < 16; ++j) v[j] = xr[lane + j * 64];
  float mn = 0.f, mx = 0.f;  // reference clamps min<=0, max>=0
#pragma unroll
  for (int j = 0; j < 16; ++j) {
    mn = fminf(mn, fminf(fminf(v[j].x, v[j].y), fminf(v[j].z, v[j].w)));
    mx = fmaxf(mx, fmaxf(fmaxf(v[j].x, v[j].y), fmaxf(v[j].z, v[j].w)));
  }
#pragma unroll
  for (int off = 32; off > 0; off >>= 1) {
    mn = fminf(mn, __shfl_xor(mn, off));
    mx = fmaxf(mx, __shfl_xor(mx, off));
  }
  const float scale = fmaxf((mx - mn) / 255.0f, 1.1920928955078125e-07f);
  const float dmin = mn / scale, dmax = mx / scale;
  float zp = ((-128.0f + dmin) + (127.0f + dmax) > 0.0f) ? (-128.0f - dmin)
                                                         : (127.0f - dmax);
  zp = rintf(fminf(fmaxf(zp, -128.0f), 127.0f));  // jnp.round = RNE
  const float rs = 1.0f / scale;
  if (lane == 0) {
    sct[row] = scale;
    zpt[row] = zp;
  }
  int* xo = (int*)(xq + (size_t)row * I);
#pragma unroll
  for (int j = 0; j < 16; ++j) {
    const float q0 = fminf(fmaxf(rintf(v[j].x * rs) + zp, -128.f), 127.f);
    const float q1 = fminf(fmaxf(rintf(v[j].y * rs) + zp, -128.f), 127.f);
    const float q2 = fminf(fmaxf(rintf(v[j].z * rs) + zp, -128.f), 127.f);
    const float q3 = fminf(fmaxf(rintf(v[j].w * rs) + zp, -128.f), 127.f);
    xo[lane + j * 64] = ((int)q0 & 255) | (((int)q1 & 255) << 8) |
                        (((int)q2 & 255) << 16) | ((int)q3 << 24);
  }
}

// ---------------- prep_w: w' = w - z as i8, plus U_o = sum_g s_g*sum(w') ---
__global__ __launch_bounds__(256) void prep_w(const int* __restrict__ w,
                                              const float* __restrict__ scales,
                                              const float* __restrict__ zeros,
                                              char* __restrict__ wq,
                                              float* __restrict__ U) {
  __shared__ float sg[32];
  const int tid = threadIdx.x;
  const int wave = tid >> 6, lane = tid & 63;
  const long long base = (long long)blockIdx.x * 2048 + tid;
  const int4* wr = (const int4*)w;
  int* wo = (int*)wq;
  int4 wv[8];
#pragma unroll
  for (int it = 0; it < 8; ++it) wv[it] = wr[base + (size_t)it * 256];
#pragma unroll
  for (int it = 0; it < 8; ++it) {
    const long long c = base + (size_t)it * 256;
    const int g = __builtin_amdgcn_readfirstlane((int)(c >> 6));
    const float s = scales[g];
    const int zi = (int)zeros[g];  // zeros integral -> exact
    const int a0 = wv[it].x - zi, a1 = wv[it].y - zi;
    const int a2 = wv[it].z - zi, a3 = wv[it].w - zi;
    wo[c] = (a0 & 255) | ((a1 & 255) << 8) | ((a2 & 255) << 16) | (a3 << 24);
    int cs = a0 + a1 + a2 + a3;
#pragma unroll
    for (int off = 32; off > 0; off >>= 1) cs += __shfl_xor(cs, off);
    if (lane == 0) sg[wave + it * 4] = s * (float)cs;  // local group idx
  }
  __syncthreads();
  if (tid < 2) {
    float u = 0.f;
#pragma unroll
    for (int k = 0; k < 16; ++k) u += sg[tid * 16 + k];
    U[blockIdx.x * 2 + tid] = u;
  }
}

// ---------------- i8 NT GEMM: 256x256 tile, BKB=128, 8 waves, 8-phase ------
// C[t,o] = sct[t]*(sum_g s[o,g]*dot_g(q,w') - zpt[t]*U[o]).
// R5 fix vs R4: B fragments for ALL FOUR n-quadrants stay in registers
// (b[4][2], loaded at phases 1-2, reused at phases 3-4) exactly like the
// verified R3 bf16 schedule. R4 re-read B n0-1 from Bs[CUR] at phase 4,
// racing with phase 3's STAGE_B(CUR, ..., kt+2) overwrite -> corruption.
__global__ __launch_bounds__(512, 2) void gemm_i8(
    const char* __restrict__ A, const char* __restrict__ B,
    const float* __restrict__ scales, const float* __restrict__ sct,
    const float* __restrict__ zpt, const float* __restrict__ U,
    float* __restrict__ C, int N, int K, int G) {
  __shared__ __align__(16) char As[2][BM * BKB];
  __shared__ __align__(16) char Bs[2][BN * BKB];
  __shared__ __align__(16) float scl[BN * 16];  // [col][g], assumes G==16
  const int tid = threadIdx.x;
  const int wave = tid >> 6, lane = tid & 63;
  const int wm = wave >> 2;  // 0..1  M half (128 rows)
  const int wn = wave & 3;   // 0..3  N quarter (64 cols)

  // XCD-aware bijective swizzle (nwg % 8 == 0 here: 512 blocks)
  const int nwg = gridDim.x;
  const int bid = blockIdx.x;
  const int swz =
      ((nwg & 7) == 0) ? ((bid & 7) * (nwg >> 3) + (bid >> 3)) : bid;
  const int ntn = N / BN;
  const int by = swz / ntn, bx = swz % ntn;
  const int bm0 = by * BM, bn0 = bx * BN;

  // staging: physical 16B chunk c of LDS row r holds logical chunk c^(r&7)
  const int ldr = lane >> 3;
  const int ldc = ((lane & 7) ^ ldr) * 16;  // bytes
  const char* Ag = A + (size_t)(bm0 + wave * 16 + ldr) * K + ldc;
  const char* Bg = B + (size_t)(bn0 + wave * 16 + ldr) * K + ldc;

#define STAGE_A(b_, h, kt)                                        \
  do {                                                            \
    glds16(Ag + (size_t)((h) * 128) * K + (size_t)(kt) * BKB,     \
           &As[b_][((h) * 128 + wave * 16) * BKB]);               \
    glds16(Ag + (size_t)((h) * 128 + 8) * K + (size_t)(kt) * BKB, \
           &As[b_][((h) * 128 + wave * 16 + 8) * BKB]);           \
  } while (0)
#define STAGE_B(b_, h, kt)                                        \
  do {                                                            \
    glds16(Bg + (size_t)((h) * 128) * K + (size_t)(kt) * BKB,     \
           &Bs[b_][((h) * 128 + wave * 16) * BKB]);               \
    glds16(Bg + (size_t)((h) * 128 + 8) * K + (size_t)(kt) * BKB, \
           &Bs[b_][((h) * 128 + wave * 16 + 8) * BKB]);           \
  } while (0)

  // fragment reads: lane holds row lane&15, k-bytes [(lane>>4)*16, +16)
  const int mrow = lane & 15;
  const int kc = lane >> 4;
  const int sw = mrow & 7;
  const int c0 = ((kc) ^ sw) * 16;      // ks=0 physical chunk byte offset
  const int c1 = ((4 + kc) ^ sw) * 16;  // ks=1
  const int aBase = (wm * 128 + mrow) * BKB;
  const int bBase = (wn * 64 + mrow) * BKB;
  const int col = lane & 15;

  // ---- prologue: fill scl (block's 256 cols x 16 groups of scales) ----
  {
    const float4* sp = (const float4*)(scales + (size_t)bn0 * G);
    float4* sd = (float4*)scl;
    sd[tid] = sp[tid];
    sd[tid + 512] = sp[tid + 512];
  }

  f32x4 acc[8][4];
#pragma unroll
  for (int i = 0; i < 8; ++i)
#pragma unroll
    for (int j = 0; j < 4; ++j) acc[i][j] = (f32x4){0.f, 0.f, 0.f, 0.f};

  const int NT = K / BKB;  // 32 for K=4096 (even, >= 4)

  STAGE_A(0, 0, 0);
  STAGE_A(0, 1, 0);
  STAGE_B(0, 0, 0);
  STAGE_B(0, 1, 0);
  STAGE_B(1, 0, 1);
  STAGE_B(1, 1, 1);
  asm volatile("s_waitcnt vmcnt(4)" ::: "memory");
  asm volatile("s_waitcnt lgkmcnt(0)" ::: "memory");  // scl ds_writes done
  __builtin_amdgcn_sched_barrier(0);
  __builtin_amdgcn_s_barrier();

  i32x4 a[4][2], b[4][2], qd[4][2];
  float ssv[4];

// 16 MFMA: one C-quadrant x K=128 (two chained K=64 per fragment, C=0 start)
#define MMQ(NI0)                                                          \
  __builtin_amdgcn_s_setprio(1);                                          \
  _Pragma("unroll") for (int mi = 0; mi < 4; ++mi)                        \
      _Pragma("unroll") for (int nj = 0; nj < 2; ++nj) {                  \
    i32x4 t0 = __builtin_amdgcn_mfma_i32_16x16x64_i8(                     \
        a[mi][0], b[(NI0) + nj][0], (i32x4){0, 0, 0, 0}, 0, 0, 0);        \
    qd[mi][nj] = __builtin_amdgcn_mfma_i32_16x16x64_i8(                   \
        a[mi][1], b[(NI0) + nj][1], t0, 0, 0, 0);                         \
  }                                                                       \
  __builtin_amdgcn_s_setprio(0);

// fold i32 quadrant partial into f32 master with group scale (exact: the
// K=128 partial is < 2^18 in magnitude, exactly representable in f32)
#define FOLD(MI0, NI0)                                                 \
  _Pragma("unroll") for (int mi = 0; mi < 4; ++mi)                     \
      _Pragma("unroll") for (int nj = 0; nj < 2; ++nj) {               \
    const float sv = ssv[(NI0) + nj];                                  \
    _Pragma("unroll") for (int r = 0; r < 4; ++r)                      \
        acc[(MI0) + mi][(NI0) + nj][r] += sv * (float)qd[mi][nj][r];   \
  }

#define LDB2(NI0, GK)                                                       \
  _Pragma("unroll") for (int nj = 0; nj < 2; ++nj) {                        \
    b[(NI0) + nj][0] =                                                      \
        *(const i32x4*)&Bc[bBase + ((NI0) + nj) * (16 * BKB) + c0];         \
    b[(NI0) + nj][1] =                                                      \
        *(const i32x4*)&Bc[bBase + ((NI0) + nj) * (16 * BKB) + c1];         \
    ssv[(NI0) + nj] = scl[(wn * 64 + ((NI0) + nj) * 16 + col) * 16 + (GK)]; \
  }
#define LDA(MI0)                                                           \
  _Pragma("unroll") for (int mi = 0; mi < 4; ++mi) {                       \
    a[mi][0] = *(const i32x4*)&Ac[aBase + ((MI0) + mi) * (16 * BKB) + c0]; \
    a[mi][1] = *(const i32x4*)&Ac[aBase + ((MI0) + mi) * (16 * BKB) + c1]; \
  }

#define KTILE(CUR, KT, DO_SA, DO_SB, WAIT4)            \
  do {                                                 \
    const char* Ac = As[CUR];                          \
    const char* Bc = Bs[CUR];                          \
    const int gk = (KT) >> 1;                          \
    /* phase 1: (m0-3) x (n0-1) */                     \
    LDA(0)                                             \
    LDB2(0, gk)                                        \
    if (DO_SA) STAGE_A(1 - (CUR), 0, (KT) + 1);        \
    __builtin_amdgcn_s_barrier();                      \
    MMQ(0)                                             \
    FOLD(0, 0)                                         \
    __builtin_amdgcn_s_barrier();                      \
    /* phase 2: (m0-3) x (n2-3) */                     \
    LDB2(2, gk)                                        \
    if (DO_SA) STAGE_A(1 - (CUR), 1, (KT) + 1);        \
    __builtin_amdgcn_s_barrier();                      \
    MMQ(2)                                             \
    FOLD(0, 2)                                         \
    __builtin_amdgcn_s_barrier();                      \
    /* phase 3: (m4-7) x (n2-3); B-of-cur LDS reads ended at phase 2 */ \
    LDA(4)                                             \
    if (DO_SB) STAGE_B(CUR, 0, (KT) + 2);              \
    __builtin_amdgcn_s_barrier();                      \
    MMQ(2)                                             \
    FOLD(4, 2)                                         \
    __builtin_amdgcn_s_barrier();                      \
    /* phase 4: (m4-7) x (n0-1); register reuse, NO LDS reads */ \
    if (DO_SB) STAGE_B(CUR, 1, (KT) + 2);              \
    if (WAIT4)                                         \
      asm volatile("s_waitcnt vmcnt(4)" ::: "memory"); \
    else                                               \
      asm volatile("s_waitcnt vmcnt(0)" ::: "memory"); \
    __builtin_amdgcn_sched_barrier(0);                 \
    __builtin_amdgcn_s_barrier();                      \
    MMQ(0)                                             \
    FOLD(4, 0)                                         \
    __builtin_amdgcn_s_barrier();                      \
  } while (0)

  int kt = 0;
  for (; kt < NT - 2; kt += 2) {
    KTILE(0, kt, 1, 1, 1);
    KTILE(1, kt + 1, 1, 1, 1);
  }
  KTILE(0, kt, 1, 0, 0);
  KTILE(1, kt + 1, 0, 0, 0);

  // epilogue: out = sct[r]*(acc - zpt[r]*U[c]); C/D layout col=lane&15,
  // row=(lane>>4)*4+reg (dtype-independent)
  const int rq = (lane >> 4) * 4;
  float un[4];
#pragma unroll
  for (int ni = 0; ni < 4; ++ni) un[ni] = U[bn0 + wn * 64 + ni * 16 + col];
#pragma unroll
  for (int mi = 0; mi < 8; ++mi) {
    const int r0 = bm0 + wm * 128 + mi * 16 + rq;
#pragma unroll
    for (int r = 0; r < 4; ++r) {
      const float sc = sct[r0 + r];
      const float zp = zpt[r0 + r];
#pragma unroll
      for (int ni = 0; ni < 4; ++ni) {
        const int c = bn0 + wn * 64 + ni * 16 + col;
        C[(size_t)(r0 + r) * N + c] = sc * (acc[mi][ni][r] - zp * un[ni]);
      }
    }
  }
#undef KTILE
#undef LDA
#undef LDB2
#undef FOLD
#undef MMQ
#undef STAGE_A
#undef STAGE_B
}

extern "C" void kernel_launch(void* const* d_in, const int* in_sizes, int n_in,
                              void* d_out, int out_size, void* d_ws,
                              size_t ws_size, hipStream_t stream) {
  const float* x = (const float*)d_in[0];
  const int* w = (const int*)d_in[1];
  const float* scales = (const float*)d_in[2];
  const float* zeros = (const float*)d_in[3];
  float* out = (float*)d_out;

  const double ii =
      sqrt((double)in_sizes[0] * (double)in_sizes[1] / (double)out_size);
  const int I = (int)(ii + 0.5);
  const int T = in_sizes[0] / I;
  const int O = in_sizes[1] / I;
  const int G = I / 256;

  char* xqi = (char*)d_ws;             // T*I i8
  char* wqi = xqi + (size_t)T * I;     // O*I i8
  float* sct = (float*)(wqi + (size_t)O * I);  // T
  float* zpt = sct + T;                // T
  float* U = zpt + T;                  // O

  prep_x<<<T / 4, 256, 0, stream>>>(x, xqi, sct, zpt, I);
  prep_w<<<(int)(((long long)O * I) >> 13), 256, 0, stream>>>(w, scales,
                                                              zeros, wqi, U);
  gemm_i8<<<(O / BN) * (T / BM), 512, 0, stream>>>(xqi, wqi, scales, sct, zpt,
                                                   U, out, O, I, G);
}

// Round 6
// 1006.234 us; speedup vs baseline: 1.3437x; 1.3437x over previous
//
#include <hip/hip_runtime.h>
#include <hip/hip_bf16.h>
#include <math.h>

typedef __attribute__((ext_vector_type(4))) int i32x4;
typedef __attribute__((ext_vector_type(4))) float f32x4;

#define BM 256
#define BN 256
#define BKB 128  // K-bytes per tile = 128 int8 elements

__device__ __forceinline__ void glds16(const void* g, void* l) {
  __builtin_amdgcn_global_load_lds(
      (const __attribute__((address_space(1))) void*)g,
      (__attribute__((address_space(3))) void*)l, 16, 0, 0);
}

// ---------------- prep_x: per-token int8 quant, store q as i8 --------------
__global__ __launch_bounds__(256) void prep_x(const float* __restrict__ x,
                                              char* __restrict__ xq,
                                              float* __restrict__ sct,
                                              float* __restrict__ zpt,
                                              int I) {
  const int wave = threadIdx.x >> 6, lane = threadIdx.x & 63;
  const int row = blockIdx.x * 4 + wave;
  const float4* xr = (const float4*)(x + (size_t)row * I);
  float4 v[16];  // I/4 float4 per row / 64 lanes = 16 (I = 4096)
#pragma unroll
  for (int j = 0; j < 16; ++j) v[j] = xr[lane + j * 64];
  float mn = 0.f, mx = 0.f;  // reference clamps min<=0, max>=0
#pragma unroll
  for (int j = 0; j < 16; ++j) {
    mn = fminf(mn, fminf(fminf(v[j].x, v[j].y), fminf(v[j].z, v[j].w)));
    mx = fmaxf(mx, fmaxf(fmaxf(v[j].x, v[j].y), fmaxf(v[j].z, v[j].w)));
  }
#pragma unroll
  for (int off = 32; off > 0; off >>= 1) {
    mn = fminf(mn, __shfl_xor(mn, off));
    mx = fmaxf(mx, __shfl_xor(mx, off));
  }
  const float scale = fmaxf((mx - mn) / 255.0f, 1.1920928955078125e-07f);
  const float dmin = mn / scale, dmax = mx / scale;
  float zp = ((-128.0f + dmin) + (127.0f + dmax) > 0.0f) ? (-128.0f - dmin)
                                                         : (127.0f - dmax);
  zp = rintf(fminf(fmaxf(zp, -128.0f), 127.0f));  // jnp.round = RNE
  const float rs = 1.0f / scale;
  if (lane == 0) {
    sct[row] = scale;
    zpt[row] = zp;
  }
  int* xo = (int*)(xq + (size_t)row * I);
#pragma unroll
  for (int j = 0; j < 16; ++j) {
    const float q0 = fminf(fmaxf(rintf(v[j].x * rs) + zp, -128.f), 127.f);
    const float q1 = fminf(fmaxf(rintf(v[j].y * rs) + zp, -128.f), 127.f);
    const float q2 = fminf(fmaxf(rintf(v[j].z * rs) + zp, -128.f), 127.f);
    const float q3 = fminf(fmaxf(rintf(v[j].w * rs) + zp, -128.f), 127.f);
    xo[lane + j * 64] = ((int)q0 & 255) | (((int)q1 & 255) << 8) |
                        (((int)q2 & 255) << 16) | ((int)q3 << 24);
  }
}

// ---------------- prep_w: w' = w - z as i8, plus U_o = sum_g s_g*sum(w') ---
__global__ __launch_bounds__(256) void prep_w(const int* __restrict__ w,
                                              const float* __restrict__ scales,
                                              const float* __restrict__ zeros,
                                              char* __restrict__ wq,
                                              float* __restrict__ U) {
  __shared__ float sg[32];
  const int tid = threadIdx.x;
  const int wave = tid >> 6, lane = tid & 63;
  const long long base = (long long)blockIdx.x * 2048 + tid;
  const int4* wr = (const int4*)w;
  int* wo = (int*)wq;
  int4 wv[8];
#pragma unroll
  for (int it = 0; it < 8; ++it) wv[it] = wr[base + (size_t)it * 256];
#pragma unroll
  for (int it = 0; it < 8; ++it) {
    const long long c = base + (size_t)it * 256;
    const int g = __builtin_amdgcn_readfirstlane((int)(c >> 6));
    const float s = scales[g];
    const int zi = (int)zeros[g];  // zeros integral -> exact
    const int a0 = wv[it].x - zi, a1 = wv[it].y - zi;
    const int a2 = wv[it].z - zi, a3 = wv[it].w - zi;
    wo[c] = (a0 & 255) | ((a1 & 255) << 8) | ((a2 & 255) << 16) | (a3 << 24);
    int cs = a0 + a1 + a2 + a3;
#pragma unroll
    for (int off = 32; off > 0; off >>= 1) cs += __shfl_xor(cs, off);
    if (lane == 0) sg[wave + it * 4] = s * (float)cs;  // local group idx
  }
  __syncthreads();
  if (tid < 2) {
    float u = 0.f;
#pragma unroll
    for (int k = 0; k < 16; ++k) u += sg[tid * 16 + k];
    U[blockIdx.x * 2 + tid] = u;
  }
}

// ---------------- i8 NT GEMM: 256x256 tile, BKB=128, 8 waves, 8-phase ------
// C[t,o] = sct[t]*(sum_g s[o,g]*dot_g(q,w') - zpt[t]*U[o]).
// R6 fixes vs R5 (schedule/staging/barriers identical to the PASSING R5):
//  - register-pressure fix: the i32 partials (t0,q) are transient inside a
//    fused MFMA-pair+fold per fragment (was qd[4][2] held across the whole
//    phase). Demand ~228 regs <= the 256 cap of launch_bounds(512,2) ->
//    no scratch spills (R5: ~280 -> 2.3 GB/dispatch spill traffic).
//  - scale tile transposed to sclT[g][col]: lane stride 4 B -> bank-
//    conflict-free (R5 layout had 64 B stride -> 8-way, 7.3M conflicts).
__global__ __launch_bounds__(512, 2) void gemm_i8(
    const char* __restrict__ A, const char* __restrict__ B,
    const float* __restrict__ scales, const float* __restrict__ sct,
    const float* __restrict__ zpt, const float* __restrict__ U,
    float* __restrict__ C, int N, int K, int G) {
  __shared__ __align__(16) char As[2][BM * BKB];
  __shared__ __align__(16) char Bs[2][BN * BKB];
  __shared__ __align__(16) float sclT[16 * BN];  // [g][col], assumes G==16
  const int tid = threadIdx.x;
  const int wave = tid >> 6, lane = tid & 63;
  const int wm = wave >> 2;  // 0..1  M half (128 rows)
  const int wn = wave & 3;   // 0..3  N quarter (64 cols)

  // XCD-aware bijective swizzle (nwg % 8 == 0 here: 512 blocks)
  const int nwg = gridDim.x;
  const int bid = blockIdx.x;
  const int swz =
      ((nwg & 7) == 0) ? ((bid & 7) * (nwg >> 3) + (bid >> 3)) : bid;
  const int ntn = N / BN;
  const int by = swz / ntn, bx = swz % ntn;
  const int bm0 = by * BM, bn0 = bx * BN;

  // staging: physical 16B chunk c of LDS row r holds logical chunk c^(r&7)
  const int ldr = lane >> 3;
  const int ldc = ((lane & 7) ^ ldr) * 16;  // bytes
  const char* Ag = A + (size_t)(bm0 + wave * 16 + ldr) * K + ldc;
  const char* Bg = B + (size_t)(bn0 + wave * 16 + ldr) * K + ldc;

#define STAGE_A(b_, h, kt)                                        \
  do {                                                            \
    glds16(Ag + (size_t)((h) * 128) * K + (size_t)(kt) * BKB,     \
           &As[b_][((h) * 128 + wave * 16) * BKB]);               \
    glds16(Ag + (size_t)((h) * 128 + 8) * K + (size_t)(kt) * BKB, \
           &As[b_][((h) * 128 + wave * 16 + 8) * BKB]);           \
  } while (0)
#define STAGE_B(b_, h, kt)                                        \
  do {                                                            \
    glds16(Bg + (size_t)((h) * 128) * K + (size_t)(kt) * BKB,     \
           &Bs[b_][((h) * 128 + wave * 16) * BKB]);               \
    glds16(Bg + (size_t)((h) * 128 + 8) * K + (size_t)(kt) * BKB, \
           &Bs[b_][((h) * 128 + wave * 16 + 8) * BKB]);           \
  } while (0)

  // fragment reads: lane holds row lane&15, k-bytes [(lane>>4)*16, +16)
  const int mrow = lane & 15;
  const int kc = lane >> 4;
  const int sw = mrow & 7;
  const int c0 = ((kc) ^ sw) * 16;      // ks=0 physical chunk byte offset
  const int c1 = ((4 + kc) ^ sw) * 16;  // ks=1
  const int aBase = (wm * 128 + mrow) * BKB;
  const int bBase = (wn * 64 + mrow) * BKB;
  const int col = lane & 15;

  // ---- prologue: fill sclT transposed (block's 16 groups x 256 cols) ----
  {
#pragma unroll
    for (int r = 0; r < 8; ++r) {
      const int idx = tid + r * 512;
      const int cc = idx & 255, gg = idx >> 8;
      sclT[gg * BN + cc] = scales[(size_t)(bn0 + cc) * G + gg];
    }
  }

  f32x4 acc[8][4];
#pragma unroll
  for (int i = 0; i < 8; ++i)
#pragma unroll
    for (int j = 0; j < 4; ++j) acc[i][j] = (f32x4){0.f, 0.f, 0.f, 0.f};

  const int NT = K / BKB;  // 32 for K=4096 (even, >= 4)

  STAGE_A(0, 0, 0);
  STAGE_A(0, 1, 0);
  STAGE_B(0, 0, 0);
  STAGE_B(0, 1, 0);
  STAGE_B(1, 0, 1);
  STAGE_B(1, 1, 1);
  asm volatile("s_waitcnt vmcnt(4)" ::: "memory");
  asm volatile("s_waitcnt lgkmcnt(0)" ::: "memory");  // sclT ds_writes done
  __builtin_amdgcn_sched_barrier(0);
  __builtin_amdgcn_s_barrier();

  i32x4 a[4][2], b[4][2];
  float ssv[4];

// fused quadrant compute: per fragment (mi,nj): 2 chained K=64 i8 MFMAs
// (C=0 start) then immediate fold into the f32 master with the group
// scale. i32 partial |.| <= 128*128*12 < 2^24 -> cvt exact. Transient
// t0/q live only within one iteration -> minimal register pressure; the
// 8 independent iterations let the compiler pipeline MFMA vs fold VALU.
#define MMF(MI0, NI0)                                                     \
  __builtin_amdgcn_s_setprio(1);                                          \
  _Pragma("unroll") for (int mi = 0; mi < 4; ++mi)                        \
      _Pragma("unroll") for (int nj = 0; nj < 2; ++nj) {                  \
    i32x4 t0 = __builtin_amdgcn_mfma_i32_16x16x64_i8(                     \
        a[mi][0], b[(NI0) + nj][0], (i32x4){0, 0, 0, 0}, 0, 0, 0);        \
    i32x4 q = __builtin_amdgcn_mfma_i32_16x16x64_i8(                      \
        a[mi][1], b[(NI0) + nj][1], t0, 0, 0, 0);                         \
    const float sv = ssv[(NI0) + nj];                                     \
    _Pragma("unroll") for (int r = 0; r < 4; ++r)                         \
        acc[(MI0) + mi][(NI0) + nj][r] += sv * (float)q[r];               \
  }                                                                       \
  __builtin_amdgcn_s_setprio(0);

#define LDB2(NI0, GK)                                                       \
  _Pragma("unroll") for (int nj = 0; nj < 2; ++nj) {                        \
    b[(NI0) + nj][0] =                                                      \
        *(const i32x4*)&Bc[bBase + ((NI0) + nj) * (16 * BKB) + c0];         \
    b[(NI0) + nj][1] =                                                      \
        *(const i32x4*)&Bc[bBase + ((NI0) + nj) * (16 * BKB) + c1];         \
    ssv[(NI0) + nj] =                                                       \
        sclT[(GK)*BN + wn * 64 + ((NI0) + nj) * 16 + col];                  \
  }
#define LDA(MI0)                                                           \
  _Pragma("unroll") for (int mi = 0; mi < 4; ++mi) {                       \
    a[mi][0] = *(const i32x4*)&Ac[aBase + ((MI0) + mi) * (16 * BKB) + c0]; \
    a[mi][1] = *(const i32x4*)&Ac[aBase + ((MI0) + mi) * (16 * BKB) + c1]; \
  }

#define KTILE(CUR, KT, DO_SA, DO_SB, WAIT4)            \
  do {                                                 \
    const char* Ac = As[CUR];                          \
    const char* Bc = Bs[CUR];                          \
    const int gk = (KT) >> 1;                          \
    /* phase 1: (m0-3) x (n0-1) */                     \
    LDA(0)                                             \
    LDB2(0, gk)                                        \
    if (DO_SA) STAGE_A(1 - (CUR), 0, (KT) + 1);        \
    __builtin_amdgcn_s_barrier();                      \
    MMF(0, 0)                                          \
    __builtin_amdgcn_s_barrier();                      \
    /* phase 2: (m0-3) x (n2-3) */                     \
    LDB2(2, gk)                                        \
    if (DO_SA) STAGE_A(1 - (CUR), 1, (KT) + 1);        \
    __builtin_amdgcn_s_barrier();                      \
    MMF(0, 2)                                          \
    __builtin_amdgcn_s_barrier();                      \
    /* phase 3: (m4-7) x (n2-3); B-of-cur LDS reads ended at phase 2 */ \
    LDA(4)                                             \
    if (DO_SB) STAGE_B(CUR, 0, (KT) + 2);              \
    __builtin_amdgcn_s_barrier();                      \
    MMF(4, 2)                                          \
    __builtin_amdgcn_s_barrier();                      \
    /* phase 4: (m4-7) x (n0-1); register reuse, NO LDS reads */ \
    if (DO_SB) STAGE_B(CUR, 1, (KT) + 2);              \
    if (WAIT4)                                         \
      asm volatile("s_waitcnt vmcnt(4)" ::: "memory"); \
    else                                               \
      asm volatile("s_waitcnt vmcnt(0)" ::: "memory"); \
    __builtin_amdgcn_sched_barrier(0);                 \
    __builtin_amdgcn_s_barrier();                      \
    MMF(4, 0)                                          \
    __builtin_amdgcn_s_barrier();                      \
  } while (0)

  int kt = 0;
  for (; kt < NT - 2; kt += 2) {
    KTILE(0, kt, 1, 1, 1);
    KTILE(1, kt + 1, 1, 1, 1);
  }
  KTILE(0, kt, 1, 0, 0);
  KTILE(1, kt + 1, 0, 0, 0);

  // epilogue: out = sct[r]*(acc - zpt[r]*U[c]); C/D layout col=lane&15,
  // row=(lane>>4)*4+reg (dtype-independent)
  const int rq = (lane >> 4) * 4;
  float un[4];
#pragma unroll
  for (int ni = 0; ni < 4; ++ni) un[ni] = U[bn0 + wn * 64 + ni * 16 + col];
#pragma unroll
  for (int mi = 0; mi < 8; ++mi) {
    const int r0 = bm0 + wm * 128 + mi * 16 + rq;
#pragma unroll
    for (int r = 0; r < 4; ++r) {
      const float sc = sct[r0 + r];
      const float zp = zpt[r0 + r];
#pragma unroll
      for (int ni = 0; ni < 4; ++ni) {
        const int c = bn0 + wn * 64 + ni * 16 + col;
        C[(size_t)(r0 + r) * N + c] = sc * (acc[mi][ni][r] - zp * un[ni]);
      }
    }
  }
#undef KTILE
#undef LDA
#undef LDB2
#undef MMF
#undef STAGE_A
#undef STAGE_B
}

extern "C" void kernel_launch(void* const* d_in, const int* in_sizes, int n_in,
                              void* d_out, int out_size, void* d_ws,
                              size_t ws_size, hipStream_t stream) {
  const float* x = (const float*)d_in[0];
  const int* w = (const int*)d_in[1];
  const float* scales = (const float*)d_in[2];
  const float* zeros = (const float*)d_in[3];
  float* out = (float*)d_out;

  const double ii =
      sqrt((double)in_sizes[0] * (double)in_sizes[1] / (double)out_size);
  const int I = (int)(ii + 0.5);
  const int T = in_sizes[0] / I;
  const int O = in_sizes[1] / I;
  const int G = I / 256;

  char* xqi = (char*)d_ws;             // T*I i8
  char* wqi = xqi + (size_t)T * I;     // O*I i8
  float* sct = (float*)(wqi + (size_t)O * I);  // T
  float* zpt = sct + T;                // T
  float* U = zpt + T;                  // O

  prep_x<<<T / 4, 256, 0, stream>>>(x, xqi, sct, zpt, I);
  prep_w<<<(int)(((long long)O * I) >> 13), 256, 0, stream>>>(w, scales,
                                                              zeros, wqi, U);
  gemm_i8<<<(O / BN) * (T / BM), 512, 0, stream>>>(xqi, wqi, scales, sct, zpt,
                                                   U, out, O, I, G);
}